// Round 2
// baseline (48.170 us; speedup 1.0000x reference)
//
#include <hip/hip_runtime.h>

#define QN_F (-127.0f)
#define QP_F (127.0f)
#define MSB 128

__global__ void quant_main_kernel(const float4* __restrict__ w4,
                                  const float* __restrict__ alpha,
                                  float4* __restrict__ out4,
                                  int n4) {
    const float a = fmaxf(alpha[0], 1e-4f);
    int idx = blockIdx.x * blockDim.x + threadIdx.x;
    const int stride = gridDim.x * blockDim.x;
    for (int i = idx; i < n4; i += stride) {
        float4 v = w4[i];
        float4 r;
        r.x = rintf(fminf(fmaxf(v.x / a, QN_F), QP_F)) * a;
        r.y = rintf(fminf(fmaxf(v.y / a, QN_F), QP_F)) * a;
        r.z = rintf(fminf(fmaxf(v.z / a, QN_F), QP_F)) * a;
        r.w = rintf(fminf(fmaxf(v.w / a, QN_F), QP_F)) * a;
        out4[i] = r;
    }
}

__global__ void flip_fixup_kernel(const float* __restrict__ w,
                                  const float* __restrict__ alpha,
                                  const int* __restrict__ flip_idx,
                                  float* __restrict__ out,
                                  int nf) {
    const float a = fmaxf(alpha[0], 1e-4f);
    int t = blockIdx.x * blockDim.x + threadIdx.x;
    if (t < nf) {
        int i = flip_idx[t];
        float q = fminf(fmaxf(w[i] / a, QN_F), QP_F);
        int qi = (int)q;      // truncation toward zero == astype(int32)
        qi ^= MSB;            // full-width int32 XOR, matches numpy bitwise_xor
        // round(float(qi)) == float(qi) exactly (integer-valued), then * a
        out[i] = (float)qi * a;
    }
}

extern "C" void kernel_launch(void* const* d_in, const int* in_sizes, int n_in,
                              void* d_out, int out_size, void* d_ws, size_t ws_size,
                              hipStream_t stream) {
    const float* w = (const float*)d_in[0];
    const float* alpha = (const float*)d_in[1];
    const int* flip_idx = (const int*)d_in[2];   // harness passes integers as int32
    float* out = (float*)d_out;

    const int n = in_sizes[0];          // 33554432
    const int nf = in_sizes[2];         // 3356
    const int n4 = n / 4;               // weight size is a multiple of 4

    const int block = 256;
    int grid = (n4 + block - 1) / block;
    if (grid > 2048) grid = 2048;       // grid-stride the rest
    quant_main_kernel<<<grid, block, 0, stream>>>(
        (const float4*)w, alpha, (float4*)out, n4);

    int fgrid = (nf + block - 1) / block;
    flip_fixup_kernel<<<fgrid, block, 0, stream>>>(w, alpha, flip_idx, out, nf);
}